// Round 1
// baseline (1521.359 us; speedup 1.0000x reference)
//
#include <hip/hip_runtime.h>

// Problem constants (from reference): N=100000, E=1600000, D=64, C=16
#define DD 64
#define CC 16
#define EPSILON 0.1f
#define GAMMA 0.1f

// ---------------------------------------------------------------------------
// Zero the aggregation buffer (d_ws is poisoned to 0xAA before every launch).
__global__ void zero_kernel(float4* __restrict__ p, int n4) {
    int i = blockIdx.x * blockDim.x + threadIdx.x;
    if (i < n4) p[i] = make_float4(0.f, 0.f, 0.f, 0.f);
}

// ---------------------------------------------------------------------------
// Fold W_root + (W_anti - W_anti^T - gamma*I) into one matrix W_c,
// and b_rel + b_anti into one bias b_c.
__global__ void prep_weights(const float* __restrict__ Wroot,
                             const float* __restrict__ Wanti,
                             const float* __restrict__ brel,
                             const float* __restrict__ banti,
                             float* __restrict__ Wc,
                             float* __restrict__ bc) {
    int idx = blockIdx.x * blockDim.x + threadIdx.x;
    if (idx < DD * DD) {
        int i = idx >> 6;   // row d
        int j = idx & 63;   // col k
        float v = Wroot[idx] + Wanti[idx] - Wanti[j * DD + i];
        if (i == j) v -= GAMMA;
        Wc[idx] = v;
    }
    if (idx < DD) bc[idx] = brel[idx] + banti[idx];
}

// ---------------------------------------------------------------------------
// agg[dst] += x[src] over all edges. 16 threads per edge, float4 each.
__global__ void scatter_add_kernel(const int* __restrict__ ei,
                                   const float* __restrict__ x,
                                   float* __restrict__ agg, int E) {
    int tid = blockIdx.x * blockDim.x + threadIdx.x;
    if (tid >= E * 16) return;
    int e = tid >> 4;
    int q = tid & 15;
    int src = ei[e];        // row 0 of edge_index
    int dst = ei[E + e];    // row 1 of edge_index
    float4 v = reinterpret_cast<const float4*>(x)[src * 16 + q];
    float* a = agg + dst * DD + q * 4;
    atomicAdd(a + 0, v.x);
    atomicAdd(a + 1, v.y);
    atomicAdd(a + 2, v.z);
    atomicAdd(a + 3, v.w);
}

// ---------------------------------------------------------------------------
// Per-wave dense fused kernel: one wave handles one node per iteration.
// lane d holds row d of W_rel and W_c in registers (128 VGPRs); the node's
// agg/x row values are broadcast with v_readlane. h = agg*Wrel^T + x*Wc^T + bc
// then xnew = x + eps*tanh(h); out = sigmoid(xnew*Wlin^T + blin).
__device__ __forceinline__ float rl(float v, int l) {
    return __uint_as_float(__builtin_amdgcn_readlane(__float_as_uint(v), l));
}

__global__ __launch_bounds__(256) void fused_dense(
        const float* __restrict__ x, const float* __restrict__ agg,
        const float* __restrict__ Wrel, const float* __restrict__ Wc,
        const float* __restrict__ bc, const float* __restrict__ Wlin,
        const float* __restrict__ blin, float* __restrict__ out, int N) {
    __shared__ float xsh[4][DD];
    const int lane = threadIdx.x & 63;
    const int w = threadIdx.x >> 6;

    // Per-lane weight rows (reused across all nodes this wave processes).
    float wr[DD], wc[DD];
#pragma unroll
    for (int j = 0; j < 16; ++j) {
        float4 a = reinterpret_cast<const float4*>(Wrel)[lane * 16 + j];
        wr[4 * j + 0] = a.x; wr[4 * j + 1] = a.y;
        wr[4 * j + 2] = a.z; wr[4 * j + 3] = a.w;
        float4 b = reinterpret_cast<const float4*>(Wc)[lane * 16 + j];
        wc[4 * j + 0] = b.x; wc[4 * j + 1] = b.y;
        wc[4 * j + 2] = b.z; wc[4 * j + 3] = b.w;
    }
    const int c = lane & 15;   // output class this lane computes
    const int q = lane >> 4;   // quarter of D this lane reduces
    float wl[16];
#pragma unroll
    for (int j = 0; j < 4; ++j) {
        float4 t = reinterpret_cast<const float4*>(Wlin)[c * 16 + q * 4 + j];
        wl[4 * j + 0] = t.x; wl[4 * j + 1] = t.y;
        wl[4 * j + 2] = t.z; wl[4 * j + 3] = t.w;
    }
    const float blc = blin[c];
    const float bcl = bc[lane];

    const int stride = gridDim.x * 4;                 // nodes per sweep
    const int iters = (N + stride - 1) / stride;      // uniform for all blocks
    for (int t = 0; t < iters; ++t) {
        int n = t * stride + blockIdx.x * 4 + w;      // wave-uniform
        bool act = n < N;                             // wave-uniform
        float av = 0.f, xv = 0.f;
        if (act) {
            av = agg[n * DD + lane];
            xv = x[n * DD + lane];
        }
        float acc0 = bcl, acc1 = 0.f;
#pragma unroll
        for (int k = 0; k < DD; ++k) {
            acc0 += rl(av, k) * wr[k];
            acc1 += rl(xv, k) * wc[k];
        }
        float h = acc0 + acc1;
        // tanh(h) = 1 - 2/(exp(2h)+1)  (saturates correctly at +-inf)
        float e2 = __expf(2.0f * h);
        float th = 1.0f - 2.0f / (e2 + 1.0f);
        float xn = xv + EPSILON * th;

        __syncthreads();
        xsh[w][lane] = xn;
        __syncthreads();
        float p = 0.f;
#pragma unroll
        for (int j = 0; j < 16; ++j)
            p += xsh[w][q * 16 + j] * wl[j];
        __syncthreads();
        p += __shfl_xor(p, 16);
        p += __shfl_xor(p, 32);
        if (act && lane < CC) {
            float z = p + blc;
            out[n * CC + lane] = 1.0f / (1.0f + __expf(-z));
        }
    }
}

// ---------------------------------------------------------------------------
extern "C" void kernel_launch(void* const* d_in, const int* in_sizes, int n_in,
                              void* d_out, int out_size, void* d_ws, size_t ws_size,
                              hipStream_t stream) {
    const int*   ei    = (const int*)d_in[0];
    const float* x     = (const float*)d_in[1];
    const float* Wrel  = (const float*)d_in[2];
    const float* brel  = (const float*)d_in[3];
    const float* Wroot = (const float*)d_in[4];
    const float* Wanti = (const float*)d_in[5];
    const float* banti = (const float*)d_in[6];
    const float* Wlin  = (const float*)d_in[7];
    const float* blin  = (const float*)d_in[8];
    float* out = (float*)d_out;

    const int E = in_sizes[0] / 2;
    const int N = in_sizes[1] / DD;

    // Workspace layout: agg[N*64] | Wc[64*64] | bc[64]   (~25.6 MB)
    float* agg = (float*)d_ws;
    float* Wc  = agg + (size_t)N * DD;
    float* bc  = Wc + DD * DD;

    zero_kernel<<<(N * 16 + 255) / 256, 256, 0, stream>>>((float4*)agg, N * 16);
    prep_weights<<<16, 256, 0, stream>>>(Wroot, Wanti, brel, banti, Wc, bc);
    scatter_add_kernel<<<(E * 16 + 255) / 256, 256, 0, stream>>>(ei, x, agg, E);
    fused_dense<<<512, 256, 0, stream>>>(x, agg, Wrel, Wc, bc, Wlin, blin, out, N);
}

// Round 2
// 425.975 us; speedup vs baseline: 3.5715x; 3.5715x over previous
//
#include <hip/hip_runtime.h>

// N=100000, E=1600000, D=64, C=16
#define DD 64
#define CC 16
#define EPSILON 0.1f
#define GAMMA 0.1f
#define PADX 68   // xn_sh row stride (floats): breaks d-column write conflicts, keeps 16B align
#define PADW 65   // wl_sh row stride: bank = (c+d)%32 -> conflict-free across 16 c lanes

// ---------------------------------------------------------------------------
__global__ void zero_i32(int* __restrict__ p, int n) {
    int i = blockIdx.x * blockDim.x + threadIdx.x;
    if (i < n) p[i] = 0;
}

// Build B_g[128][64]: rows 0..63 = Wrel^T, rows 64..127 = Wc^T where
// Wc = Wroot + Wanti - Wanti^T - gamma*I. Also bc = brel + banti.
__global__ void prep_weights(const float* __restrict__ Wrel,
                             const float* __restrict__ Wroot,
                             const float* __restrict__ Wanti,
                             const float* __restrict__ brel,
                             const float* __restrict__ banti,
                             float* __restrict__ B_g, float* __restrict__ bc) {
    int idx = blockIdx.x * blockDim.x + threadIdx.x;
    if (idx < 128 * 64) {
        int k = idx >> 6, d = idx & 63;
        float v;
        if (k < 64) {
            v = Wrel[d * 64 + k];
        } else {
            int j = k - 64;
            v = Wroot[d * 64 + j] + Wanti[d * 64 + j] - Wanti[j * 64 + d];
            if (d == j) v -= GAMMA;
        }
        B_g[idx] = v;
    }
    if (idx < 64) bc[idx] = brel[idx] + banti[idx];
}

// ---------------------------------------------------------------------------
__global__ void count_deg(const int* __restrict__ ei, int* __restrict__ deg, int E) {
    int e = blockIdx.x * blockDim.x + threadIdx.x;
    if (e < E) atomicAdd(&deg[ei[E + e]], 1);
}

// Per-1024-chunk sums
__global__ void scan_block_sums(const int* __restrict__ deg, int* __restrict__ bsum, int N) {
    __shared__ int sh[1024];
    int tid = threadIdx.x;
    int gi = blockIdx.x * 1024 + tid;
    sh[tid] = gi < N ? deg[gi] : 0;
    __syncthreads();
    for (int off = 512; off > 0; off >>= 1) {
        if (tid < off) sh[tid] += sh[tid + off];
        __syncthreads();
    }
    if (tid == 0) bsum[blockIdx.x] = sh[0];
}

// Exclusive scan of <=128 block sums, in place
__global__ void scan_bsum(int* __restrict__ bsum, int nb) {
    __shared__ int sh[128];
    int tid = threadIdx.x;
    int v = tid < nb ? bsum[tid] : 0;
    sh[tid] = v;
    __syncthreads();
    for (int off = 1; off < 128; off <<= 1) {
        int t_ = tid >= off ? sh[tid - off] : 0;
        __syncthreads();
        sh[tid] += t_;
        __syncthreads();
    }
    if (tid < nb) bsum[tid] = sh[tid] - v;
}

// Final: offsets[i] (exclusive) + cursor copy + offsets[N]
__global__ void scan_final(const int* __restrict__ deg, const int* __restrict__ bsum,
                           int* __restrict__ offsets, int* __restrict__ cursor, int N) {
    __shared__ int sh[1024];
    int tid = threadIdx.x;
    int gi = blockIdx.x * 1024 + tid;
    int v = gi < N ? deg[gi] : 0;
    sh[tid] = v;
    __syncthreads();
    for (int off = 1; off < 1024; off <<= 1) {
        int t_ = tid >= off ? sh[tid - off] : 0;
        __syncthreads();
        sh[tid] += t_;
        __syncthreads();
    }
    int excl = sh[tid] - v + bsum[blockIdx.x];
    if (gi < N) {
        offsets[gi] = excl;
        cursor[gi] = excl;
        if (gi == N - 1) offsets[N] = excl + v;
    }
}

__global__ void fill_csr(const int* __restrict__ ei, int* __restrict__ cursor,
                         int* __restrict__ srclist, int E) {
    int e = blockIdx.x * blockDim.x + threadIdx.x;
    if (e < E) {
        int pos = atomicAdd(&cursor[ei[E + e]], 1);
        srclist[pos] = ei[e];
    }
}

// ---------------------------------------------------------------------------
// Atomic-free gather: 16 threads per node, float4 each. Writes BOTH the
// aggregation and the node's own x into A_t in TRANSPOSED layout
// A_t[k][n] (k=0..63: agg, k=64..127: x) so the dense GEMM streams
// coalesced rows. Block = 16 nodes -> each 64B A_t line touched by one block.
__global__ __launch_bounds__(256) void gather_t(const float* __restrict__ x,
                                                const int* __restrict__ offsets,
                                                const int* __restrict__ srclist,
                                                float* __restrict__ A_t, int N) {
    int t = blockIdx.x * 256 + threadIdx.x;
    int n = t >> 4, q = t & 15;
    if (n >= N) return;
    int i0 = offsets[n], i1 = offsets[n + 1];
    float4 acc = make_float4(0.f, 0.f, 0.f, 0.f);
    const float4* x4 = (const float4*)x;
    for (int i = i0; i < i1; ++i) {
        int s = srclist[i];                 // broadcast across the 16 q-lanes
        float4 v = x4[s * 16 + q];          // 256B contiguous per (node,edge)
        acc.x += v.x; acc.y += v.y; acc.z += v.z; acc.w += v.w;
    }
    size_t Ns = (size_t)N;
    A_t[(4 * q + 0) * Ns + n] = acc.x;
    A_t[(4 * q + 1) * Ns + n] = acc.y;
    A_t[(4 * q + 2) * Ns + n] = acc.z;
    A_t[(4 * q + 3) * Ns + n] = acc.w;
    float4 xv = x4[n * 16 + q];
    A_t[(64 + 4 * q + 0) * Ns + n] = xv.x;
    A_t[(64 + 4 * q + 1) * Ns + n] = xv.y;
    A_t[(64 + 4 * q + 2) * Ns + n] = xv.z;
    A_t[(64 + 4 * q + 3) * Ns + n] = xv.w;
}

// ---------------------------------------------------------------------------
// Fused dense: h = [agg|x] @ B_g + bc ; xn = x + eps*tanh(h) ;
// out = sigmoid(xn @ Wlin^T + blin). Block = 64 nodes x 64 cols,
// thread = 4x4 tile (16 acc VGPRs). A streamed from global (coalesced,
// L3-hot), B in LDS.
__global__ __launch_bounds__(256) void dense_kernel(
        const float* __restrict__ A_t, const float* __restrict__ B_g,
        const float* __restrict__ bc, const float* __restrict__ Wlin,
        const float* __restrict__ blin, float* __restrict__ out, int N) {
    __shared__ float Bs[128 * 64];
    __shared__ float xn_sh[64 * PADX];
    __shared__ float wl_sh[16 * PADW];

    const int t = threadIdx.x;
    const int nb = blockIdx.x * 64;
    const size_t Ns = (size_t)N;

    // Stage B (32KB) and Wlin (padded) into LDS.
    {
        const float4* Bg4 = (const float4*)B_g;
        float4* Bs4 = (float4*)Bs;
#pragma unroll
        for (int r = 0; r < 8; ++r) Bs4[t + 256 * r] = Bg4[t + 256 * r];
        float4 w4 = ((const float4*)Wlin)[t];   // 256*4 = 16*64 exact
        int c = (t * 4) >> 6, d0 = (t * 4) & 63;
        wl_sh[c * PADW + d0 + 0] = w4.x;
        wl_sh[c * PADW + d0 + 1] = w4.y;
        wl_sh[c * PADW + d0 + 2] = w4.z;
        wl_sh[c * PADW + d0 + 3] = w4.w;
    }
    __syncthreads();

    const int ti = t & 15, tj = t >> 4;     // node-group, col-group
    float acc[4][4];
#pragma unroll
    for (int i = 0; i < 4; ++i)
#pragma unroll
        for (int j = 0; j < 4; ++j) acc[i][j] = 0.f;

    const float* Abase = A_t + nb + 4 * ti;
#pragma unroll 8
    for (int k = 0; k < 128; ++k) {
        float4 a = *(const float4*)(Abase + (size_t)k * Ns);
        float4 b = *(const float4*)&Bs[k * 64 + 4 * tj];
        acc[0][0] += a.x * b.x; acc[0][1] += a.x * b.y; acc[0][2] += a.x * b.z; acc[0][3] += a.x * b.w;
        acc[1][0] += a.y * b.x; acc[1][1] += a.y * b.y; acc[1][2] += a.y * b.z; acc[1][3] += a.y * b.w;
        acc[2][0] += a.z * b.x; acc[2][1] += a.z * b.y; acc[2][2] += a.z * b.z; acc[2][3] += a.z * b.w;
        acc[3][0] += a.w * b.x; acc[3][1] += a.w * b.y; acc[3][2] += a.w * b.z; acc[3][3] += a.w * b.w;
    }

    // Epilogue 1: xn = x + eps*tanh(h); stash xn tile to LDS for projection.
#pragma unroll
    for (int j = 0; j < 4; ++j) {
        int d = 4 * tj + j;
        float4 xr = *(const float4*)(A_t + (size_t)(64 + d) * Ns + nb + 4 * ti);
        float bcd = bc[d];
        float xn[4];
        float hv[4] = {acc[0][j], acc[1][j], acc[2][j], acc[3][j]};
        float xi[4] = {xr.x, xr.y, xr.z, xr.w};
#pragma unroll
        for (int i = 0; i < 4; ++i) {
            float h = hv[i] + bcd;
            float e2 = __expf(2.0f * h);
            float th = 1.0f - 2.0f / (e2 + 1.0f);
            xn[i] = xi[i] + EPSILON * th;
        }
        *(float4*)&xn_sh[d * PADX + 4 * ti] = make_float4(xn[0], xn[1], xn[2], xn[3]);
    }
    __syncthreads();

    // Epilogue 2: out[n][c] = sigmoid(xn . Wlin[c] + blin[c])
    const int c = t & 15, g = t >> 4;
    float p[4] = {0.f, 0.f, 0.f, 0.f};
    const float bl = blin[c];
#pragma unroll 8
    for (int d = 0; d < 64; ++d) {
        float w = wl_sh[c * PADW + d];
        float4 xv = *(const float4*)&xn_sh[d * PADX + 4 * g];
        p[0] += xv.x * w; p[1] += xv.y * w; p[2] += xv.z * w; p[3] += xv.w * w;
    }
#pragma unroll
    for (int i = 0; i < 4; ++i) {
        int n = nb + 4 * g + i;
        if (n < N) out[n * CC + c] = 1.0f / (1.0f + __expf(-(p[i] + bl)));
    }
}

// ---------------------------------------------------------------------------
extern "C" void kernel_launch(void* const* d_in, const int* in_sizes, int n_in,
                              void* d_out, int out_size, void* d_ws, size_t ws_size,
                              hipStream_t stream) {
    const int*   ei    = (const int*)d_in[0];
    const float* x     = (const float*)d_in[1];
    const float* Wrel  = (const float*)d_in[2];
    const float* brel  = (const float*)d_in[3];
    const float* Wroot = (const float*)d_in[4];
    const float* Wanti = (const float*)d_in[5];
    const float* banti = (const float*)d_in[6];
    const float* Wlin  = (const float*)d_in[7];
    const float* blin  = (const float*)d_in[8];
    float* out = (float*)d_out;

    const int E = in_sizes[0] / 2;
    const int N = in_sizes[1] / DD;

    // Workspace layout (A_t first: dense OOB tail reads stay in-bounds)
    float* A_t     = (float*)d_ws;                    // 128*N floats (51.2 MB)
    int*   offsets = (int*)(A_t + (size_t)128 * N);   // N+1
    int*   cursor  = offsets + (N + 1);               // N
    int*   deg     = cursor + N;                      // N
    int*   bsum    = deg + N;                         // 128
    int*   srclist = bsum + 128;                      // E
    float* B_g     = (float*)(srclist + E);           // 128*64
    float* bc      = B_g + 128 * 64;                  // 64

    const int NB = (N + 1023) / 1024;

    zero_i32<<<(N + 255) / 256, 256, 0, stream>>>(deg, N);
    prep_weights<<<32, 256, 0, stream>>>(Wrel, Wroot, Wanti, brel, banti, B_g, bc);
    count_deg<<<(E + 255) / 256, 256, 0, stream>>>(ei, deg, E);
    scan_block_sums<<<NB, 1024, 0, stream>>>(deg, bsum, N);
    scan_bsum<<<1, 128, 0, stream>>>(bsum, NB);
    scan_final<<<NB, 1024, 0, stream>>>(deg, bsum, offsets, cursor, N);
    fill_csr<<<(E + 255) / 256, 256, 0, stream>>>(ei, cursor, srclist, E);
    gather_t<<<(N * 16 + 255) / 256, 256, 0, stream>>>(x, offsets, srclist, A_t, N);
    dense_kernel<<<(N + 63) / 64, 256, 0, stream>>>(A_t, B_g, bc, Wlin, blin, out, N);
}